// Round 1
// baseline (232.545 us; speedup 1.0000x reference)
//
#include <hip/hip_runtime.h>

#define BATCH 512
#define SEQ   512
#define VOCAB 1000
#define EMB   100
#define UNITS 64

// ---------------------------------------------------------------------------
// Kernel 1: P[v][u] = sum_d emb[v][d] * Wxh[d][u] + b[u]   (VOCAB x UNITS)
// Hoists the entire input projection out of the time loop: xproj[b,t] depends
// only on the token id, and VOCAB=1000 << B*T=262144.
// ---------------------------------------------------------------------------
__global__ __launch_bounds__(64) void proj_kernel(
    const float* __restrict__ emb, const float* __restrict__ Wxh,
    const float* __restrict__ bias, float* __restrict__ P) {
  const int v = blockIdx.x;
  const int u = threadIdx.x;
  const float* e = emb + v * EMB;
  float acc = bias[u];
#pragma unroll 5
  for (int d = 0; d < EMB; ++d) acc += e[d] * Wxh[d * UNITS + u];
  P[v * UNITS + u] = acc;
}

// Broadcast lane `lane`'s value of x to all lanes (wave-uniform lane index
// -> v_readlane_b32 into an SGPR, consumed as scalar operand by v_fmac).
__device__ __forceinline__ float bcast(float x, int lane) {
  return __int_as_float(__builtin_amdgcn_readlane(__float_as_int(x), lane));
}

// ---------------------------------------------------------------------------
// Kernel 2: the sequential scan. One wave per batch row; lane j = unit j.
//   h[j] <- tanh(P[tok_t][j] + sum_i h[i]*Whh[i][j])
// Whh column j held in 64 VGPRs of lane j. h[i] broadcast via readlane.
// Tokens are loaded 64-at-a-time (coalesced); the next timestep's P row is
// prefetched one step ahead so its latency hides under the 64-FMA chain.
// ---------------------------------------------------------------------------
__global__ __launch_bounds__(64) void scan_kernel(
    const int* __restrict__ tok, const float* __restrict__ P,
    const float* __restrict__ Whh, const float* __restrict__ Wout,
    const float* __restrict__ bout, float* __restrict__ out) {
  const int row  = blockIdx.x;
  const int lane = threadIdx.x;

  // Whh column for this lane: wh[i] = Whh[i][lane]
  float wh[UNITS];
#pragma unroll
  for (int i = 0; i < UNITS; ++i) wh[i] = Whh[i * UNITS + lane];

  // All 512 tokens of this row, 64 per register (coalesced loads).
  int tokv[SEQ / 64];
  const int* trow = tok + row * SEQ;
#pragma unroll
  for (int c = 0; c < SEQ / 64; ++c) tokv[c] = trow[c * 64 + lane];

  float h = 0.f;

  // Prefetch P row for t=0.
  int tk0 = __builtin_amdgcn_readlane(tokv[0], 0);
  float a = P[tk0 * UNITS + lane];

#pragma unroll
  for (int c = 0; c < SEQ / 64; ++c) {
#pragma unroll 2
    for (int tt = 0; tt < 64; ++tt) {
      float a_cur = a;
      // Prefetch next timestep's P row (tt=63 issues a redundant in-chunk
      // load; the real cross-chunk prefetch happens after the loop).
      int ntt = (tt + 1) & 63;
      int tkn = __builtin_amdgcn_readlane(tokv[c], ntt);
      a = P[tkn * UNITS + lane];

      // s_j = a_cur + sum_i h[i] * Whh[i][j], 4 accumulators for ILP.
      float s0 = a_cur, s1 = 0.f, s2 = 0.f, s3 = 0.f;
#pragma unroll
      for (int i = 0; i < UNITS; i += 4) {
        s0 += bcast(h, i + 0) * wh[i + 0];
        s1 += bcast(h, i + 1) * wh[i + 1];
        s2 += bcast(h, i + 2) * wh[i + 2];
        s3 += bcast(h, i + 3) * wh[i + 3];
      }
      float s = (s0 + s1) + (s2 + s3);

      // tanh(s) = 1 - 2/(exp(2s)+1)  (safe at both extremes)
      float e = __expf(2.f * s);
      h = 1.f - 2.f / (e + 1.f);
    }
    if (c + 1 < SEQ / 64) {
      int tkb = __builtin_amdgcn_readlane(tokv[c + 1], 0);
      a = P[tkb * UNITS + lane];
    }
  }

  // out[row] = sigmoid(sum_j h[j]*Wout[j] + bout)
  float p = h * Wout[lane];
#pragma unroll
  for (int off = 32; off > 0; off >>= 1) p += __shfl_xor(p, off);
  if (lane == 0) out[row] = 1.f / (1.f + __expf(-(p + bout[0])));
}

extern "C" void kernel_launch(void* const* d_in, const int* in_sizes, int n_in,
                              void* d_out, int out_size, void* d_ws, size_t ws_size,
                              hipStream_t stream) {
  const int*   tok  = (const int*)  d_in[0];  // [BATCH, SEQ] int32
  const float* emb  = (const float*)d_in[1];  // [VOCAB, EMB]
  const float* Wxh  = (const float*)d_in[2];  // [EMB, UNITS]
  const float* Whh  = (const float*)d_in[3];  // [UNITS, UNITS]
  const float* bias = (const float*)d_in[4];  // [UNITS]
  const float* Wout = (const float*)d_in[5];  // [UNITS, 1]
  const float* bout = (const float*)d_in[6];  // [1]
  float* out = (float*)d_out;                 // [BATCH, 1] fp32

  float* P = (float*)d_ws;                    // VOCAB*UNITS fp32 = 256 KB

  proj_kernel<<<VOCAB, 64, 0, stream>>>(emb, Wxh, bias, P);
  scan_kernel<<<BATCH, 64, 0, stream>>>(tok, P, Whh, Wout, bout, out);
}